// Round 5
// baseline (117.046 us; speedup 1.0000x reference)
//
#include <hip/hip_runtime.h>
#include <math.h>

// Problem constants (fixed by the reference setup_inputs).
constexpr int B_ = 256;
constexpr int L_ = 16384;
constexpr int C_ = 4;
constexpr int THREADS = 1024;             // 16 waves/block, 1 block per row
constexpr int NVAL = 11;                  // ce, cnt, mat[9]
constexpr int NWAVE = THREADS / 64;       // 16

// Single kernel, ticket-fused final reduce.
//
// Session ledger:
//  R0: two kernels, unconditional body, per-iter loads    -> 104.8 us (best)
//  R1: guarded iters 2-3, labels loaded in-iter           -> 106.0
//  R2: spin-flag fusion (block 0 polls 256 flags)         -> 115.5 (spin
//      burns a CU + observation latency: NEVER spin-fuse)
//  R3: guarded, labels hoisted                            -> 106.4
//  R4: all 20 loads hoisted                               -> 106.7
//  Lessons: (a) pad-skip is useless — critical path = slowest block = a
//  full-length row; (b) load scheduling is compiler-saturated; (c) fill
//  drift (~+/-1 us on 82 us of harness resets) dominates small deltas.
//  Remaining structural cost: 2nd dispatch + graph gap => ticket fusion.
//
// Ticket pattern (vs R2's spin): every block increments `tick` AFTER
// publishing its row result; the block drawing ticket 255 is by definition
// the LAST one — it is already done with its own work, nobody ever waits.
// ws-poison hazard: `tick`'s initial value is unknown (harness re-poisons
// ws each iteration), so EVERY block atomicExch(tick, 0) as its first
// instruction. Idempotent. Safe because grid == 256 == CU count: all
// blocks are co-resident and start within <<1 us, while the first
// atomicAdd comes ~13 us later (>12 us margin, single dispatch wave).
__global__ __launch_bounds__(THREADS) void dmice_fused(
    const float* __restrict__ pred, const int* __restrict__ labels,
    float* __restrict__ rowout, unsigned* __restrict__ tick,
    float* __restrict__ out) {
  const int b = blockIdx.x;               // 0 .. B_-1
  const int t = threadIdx.x;
  if (t == 0) atomicExch(tick, 0u);       // idempotent poison-clear (all blocks)

  const float* p0 = pred + (size_t)b * (C_ * L_);
  const float* p1 = p0 + L_;
  const float* p2 = p0 + 2 * L_;
  const float* p3 = p0 + 3 * L_;
  const int* lb = labels + (size_t)b * L_;

  float ce = 0.f, cnt = 0.f;
  float m00 = 0.f, m01 = 0.f, m02 = 0.f;
  float m10 = 0.f, m11 = 0.f, m12 = 0.f;
  float m20 = 0.f, m21 = 0.f, m22 = 0.f;

  // Bit-identical to R0's proc (pad check per element, same op order).
  auto proc = [&](float v0, float v1, float v2, float v3, int lab) {
    float mx = fmaxf(fmaxf(v0, v1), fmaxf(v2, v3));
    float e0 = __expf(v0 - mx);
    float e1 = __expf(v1 - mx);
    float e2 = __expf(v2 - mx);
    float e3 = __expf(v3 - mx);
    float s3 = e0 + e1 + e2;
    float s4 = s3 + e3;
    if (lab != 3) {
      float xl = (lab == 0) ? v0 : ((lab == 1) ? v1 : v2);
      ce += (mx + __logf(s4)) - xl;       // -log_softmax[label]
      cnt += 1.f;
      float inv = 1.f / s3;
      float r0 = (lab == 0) ? inv : 0.f;
      float r1 = (lab == 1) ? inv : 0.f;
      float r2 = (lab == 2) ? inv : 0.f;
      m00 = fmaf(e0, r0, m00); m01 = fmaf(e1, r0, m01); m02 = fmaf(e2, r0, m02);
      m10 = fmaf(e0, r1, m10); m11 = fmaf(e1, r1, m11); m12 = fmaf(e2, r1, m12);
      m20 = fmaf(e0, r2, m20); m21 = fmaf(e1, r2, m21); m22 = fmaf(e2, r2, m22);
    }
  };

  constexpr int ITERS = L_ / (THREADS * 4);  // 4  (R0's exact loop form)
#pragma unroll
  for (int it = 0; it < ITERS; ++it) {
    const int idx = (it * THREADS + t) * 4;
    const int4 l = *(const int4*)(lb + idx);
    const float4 x0 = *(const float4*)(p0 + idx);
    const float4 x1 = *(const float4*)(p1 + idx);
    const float4 x2 = *(const float4*)(p2 + idx);
    const float4 x3 = *(const float4*)(p3 + idx);
    proc(x0.x, x1.x, x2.x, x3.x, l.x);
    proc(x0.y, x1.y, x2.y, x3.y, l.y);
    proc(x0.z, x1.z, x2.z, x3.z, l.z);
    proc(x0.w, x1.w, x2.w, x3.w, l.w);
  }

  // Reduction: wave64 shuffle, then LDS across 16 waves (identical to R0).
  float vals[NVAL] = {ce, cnt, m00, m01, m02, m10, m11, m12, m20, m21, m22};
#pragma unroll
  for (int off = 32; off > 0; off >>= 1) {
#pragma unroll
    for (int k = 0; k < NVAL; ++k) vals[k] += __shfl_down(vals[k], off, 64);
  }
  __shared__ float red[NWAVE][NVAL];
  const int wave = t >> 6, lane = t & 63;
  if (lane == 0) {
#pragma unroll
    for (int k = 0; k < NVAL; ++k) red[wave][k] = vals[k];
  }
  __syncthreads();

  __shared__ bool last;
  if (t == 0) {
    float s[NVAL];
#pragma unroll
    for (int k = 0; k < NVAL; ++k) {
      float acc = 0.f;
#pragma unroll
      for (int w = 0; w < NWAVE; ++w) acc += red[w][k];
      s[k] = acc;
    }
    float cs = s[1];
    float inv = 1.f / cs;                 // j[b] = valid count (pads suffix)
    float a00 = s[2] * inv, a01 = s[3] * inv, a02 = s[4] * inv;
    float a10 = s[5] * inv, a11 = s[6] * inv, a12 = s[7] * inv;
    float a20 = s[8] * inv, a21 = s[9] * inv, a22 = s[10] * inv;
    float det = a00 * (a11 * a22 - a12 * a21)
              - a01 * (a10 * a22 - a12 * a20)
              + a02 * (a10 * a21 - a11 * a20);
    float lg = __logf(fabsf(det) + 1e-3f);
    float dmi = (det < 0.f) ? lg : -lg;
    *(float4*)(rowout + (size_t)b * 4) = make_float4(dmi, s[0], cs, 0.f);
    __threadfence();                      // publish rowout (device scope)...
    unsigned old = atomicAdd(tick, 1u);   // ...before taking a ticket
    last = (old == (unsigned)(B_ - 1));   // ticket 255 => everyone published
  }
  __syncthreads();
  if (!last) return;

  // ---- last block only: final reduce, bit-identical to old dmice_final ----
  __threadfence();                        // acquire side: see others' rowout
  float r0 = 0.f, r1 = 0.f, r2 = 0.f;
  if (t < B_) {
    const float4 v = *(const float4*)(rowout + (size_t)t * 4);
    r0 = v.x; r1 = v.y; r2 = v.z;
  }
#pragma unroll
  for (int off = 32; off > 0; off >>= 1) {
    r0 += __shfl_down(r0, off, 64);
    r1 += __shfl_down(r1, off, 64);
    r2 += __shfl_down(r2, off, 64);
  }
  __shared__ float fin[NWAVE][3];
  if (lane == 0) { fin[wave][0] = r0; fin[wave][1] = r1; fin[wave][2] = r2; }
  __syncthreads();
  if (t == 0) {
    // Only waves 0..3 held rows (t < 256) — same 4-way sum as dmice_final.
    float dmi_s = fin[0][0] + fin[1][0] + fin[2][0] + fin[3][0];
    float ce_s  = fin[0][1] + fin[1][1] + fin[2][1] + fin[3][1];
    float cnt_s = fin[0][2] + fin[1][2] + fin[2][2] + fin[3][2];
    out[0] = 0.1f * (dmi_s * (1.f / (float)B_)) + ce_s / cnt_s;
  }
}

extern "C" void kernel_launch(void* const* d_in, const int* in_sizes, int n_in,
                              void* d_out, int out_size, void* d_ws, size_t ws_size,
                              hipStream_t stream) {
  const float* pred = (const float*)d_in[0];
  const int* labels = (const int*)d_in[1];
  float* out = (float*)d_out;
  float* rowout = (float*)d_ws;                        // B_*4 floats = 4 KiB
  unsigned* tick = (unsigned*)((char*)d_ws + 4096);    // 1 word, self-cleared

  dmice_fused<<<B_, THREADS, 0, stream>>>(pred, labels, rowout, tick, out);
}

// Round 6
// 104.854 us; speedup vs baseline: 1.1163x; 1.1163x over previous
//
#include <hip/hip_runtime.h>
#include <math.h>

// Problem constants (fixed by the reference setup_inputs).
constexpr int B_ = 256;
constexpr int L_ = 16384;
constexpr int C_ = 4;
constexpr int THREADS = 1024;             // 16 waves/block, 1 block per row
constexpr int NVAL = 11;                  // ce, cnt, mat[9]
constexpr int NWAVE = THREADS / 64;       // 16

// R0 structure restored verbatim — the session's measured best (104.8 us).
//
// Session ledger (why this exact form):
//  R0: two kernels, unconditional body, per-iter loads    -> 104.8 us  BEST
//  R1: guarded iters 2-3, labels loaded in-iter           -> 106.0
//  R2: spin-flag fusion (block 0 polls 256 flags)         -> 115.5
//  R3: guarded, labels hoisted                            -> 106.4
//  R4: all 20 loads hoisted (max MLP)                     -> 106.7
//  R5: ticket fusion (last block reduces)                 -> 117.0
//  Lessons:
//   (a) pad-skip never helps: with 1 block/row every block fetches its full
//       row anyway (unconditional) or the critical path is the full-length
//       row (guarded) — byte savings don't reach the makespan.
//   (b) load scheduling is compiler-saturated: hand-hoisting is neutral.
//   (c) single-dispatch fusion of the final reduce costs +10-12 us on
//       gfx950: device-scope fences + same-line atomics across 8
//       non-coherent XCD L2s >> a 2nd dispatch (~1.5 us + gap).
//   (d) window = 2x41 us harness fills (HBM-ceiling-bound, immutable)
//       + ~16 us row kernel (~13 us byte floor) + final + graph gaps.
__global__ __launch_bounds__(THREADS) void dmice_row(
    const float* __restrict__ pred, const int* __restrict__ labels,
    float* __restrict__ rowout) {
  const int b = blockIdx.x;               // 0 .. B_-1
  const float* p0 = pred + (size_t)b * (C_ * L_);
  const float* p1 = p0 + L_;
  const float* p2 = p0 + 2 * L_;
  const float* p3 = p0 + 3 * L_;
  const int* lb = labels + (size_t)b * L_;
  const int t = threadIdx.x;

  float ce = 0.f, cnt = 0.f;
  float m00 = 0.f, m01 = 0.f, m02 = 0.f;
  float m10 = 0.f, m11 = 0.f, m12 = 0.f;
  float m20 = 0.f, m21 = 0.f, m22 = 0.f;

  auto proc = [&](float v0, float v1, float v2, float v3, int lab) {
    float mx = fmaxf(fmaxf(v0, v1), fmaxf(v2, v3));
    float e0 = __expf(v0 - mx);
    float e1 = __expf(v1 - mx);
    float e2 = __expf(v2 - mx);
    float e3 = __expf(v3 - mx);
    float s3 = e0 + e1 + e2;
    float s4 = s3 + e3;
    if (lab != 3) {
      float xl = (lab == 0) ? v0 : ((lab == 1) ? v1 : v2);
      ce += (mx + __logf(s4)) - xl;       // -log_softmax[label]
      cnt += 1.f;
      float inv = 1.f / s3;
      float r0 = (lab == 0) ? inv : 0.f;
      float r1 = (lab == 1) ? inv : 0.f;
      float r2 = (lab == 2) ? inv : 0.f;
      m00 = fmaf(e0, r0, m00); m01 = fmaf(e1, r0, m01); m02 = fmaf(e2, r0, m02);
      m10 = fmaf(e0, r1, m10); m11 = fmaf(e1, r1, m11); m12 = fmaf(e2, r1, m12);
      m20 = fmaf(e0, r2, m20); m21 = fmaf(e1, r2, m21); m22 = fmaf(e2, r2, m22);
    }
  };

  constexpr int ITERS = L_ / (THREADS * 4);  // 4
#pragma unroll
  for (int it = 0; it < ITERS; ++it) {
    const int idx = (it * THREADS + t) * 4;
    const int4 l = *(const int4*)(lb + idx);
    const float4 x0 = *(const float4*)(p0 + idx);
    const float4 x1 = *(const float4*)(p1 + idx);
    const float4 x2 = *(const float4*)(p2 + idx);
    const float4 x3 = *(const float4*)(p3 + idx);
    proc(x0.x, x1.x, x2.x, x3.x, l.x);
    proc(x0.y, x1.y, x2.y, x3.y, l.y);
    proc(x0.z, x1.z, x2.z, x3.z, l.z);
    proc(x0.w, x1.w, x2.w, x3.w, l.w);
  }

  // Reduction: wave64 shuffle, then LDS across 16 waves.
  float vals[NVAL] = {ce, cnt, m00, m01, m02, m10, m11, m12, m20, m21, m22};
#pragma unroll
  for (int off = 32; off > 0; off >>= 1) {
#pragma unroll
    for (int k = 0; k < NVAL; ++k) vals[k] += __shfl_down(vals[k], off, 64);
  }
  __shared__ float red[NWAVE][NVAL];
  const int wave = t >> 6, lane = t & 63;
  if (lane == 0) {
#pragma unroll
    for (int k = 0; k < NVAL; ++k) red[wave][k] = vals[k];
  }
  __syncthreads();
  if (t == 0) {
    float s[NVAL];
#pragma unroll
    for (int k = 0; k < NVAL; ++k) {
      float acc = 0.f;
#pragma unroll
      for (int w = 0; w < NWAVE; ++w) acc += red[w][k];
      s[k] = acc;
    }
    float cs = s[1];
    float inv = 1.f / cs;                 // j[b] = valid count (pads are suffix)
    float a00 = s[2] * inv, a01 = s[3] * inv, a02 = s[4] * inv;
    float a10 = s[5] * inv, a11 = s[6] * inv, a12 = s[7] * inv;
    float a20 = s[8] * inv, a21 = s[9] * inv, a22 = s[10] * inv;
    float det = a00 * (a11 * a22 - a12 * a21)
              - a01 * (a10 * a22 - a12 * a20)
              + a02 * (a10 * a21 - a11 * a20);
    float lg = __logf(fabsf(det) + 1e-3f);
    float dmi = (det < 0.f) ? lg : -lg;
    *(float4*)(rowout + (size_t)b * 4) = make_float4(dmi, s[0], cs, 0.f);
  }
}

// Kernel 2: one block, thread b reads row b's {dmi, ce, cnt}, block-reduce,
// write the scalar loss.
__global__ __launch_bounds__(256) void dmice_final(
    const float* __restrict__ rowout, float* __restrict__ out) {
  const int b = threadIdx.x;  // 0..255 == B_
  const float4 v = *(const float4*)(rowout + (size_t)b * 4);
  float r[3] = {v.x, v.y, v.z};
#pragma unroll
  for (int off = 32; off > 0; off >>= 1) {
#pragma unroll
    for (int k = 0; k < 3; ++k) r[k] += __shfl_down(r[k], off, 64);
  }
  __shared__ float red[4][3];
  const int wave = b >> 6, lane = b & 63;
  if (lane == 0) {
#pragma unroll
    for (int k = 0; k < 3; ++k) red[wave][k] = r[k];
  }
  __syncthreads();
  if (b == 0) {
    float dmi_s = red[0][0] + red[1][0] + red[2][0] + red[3][0];
    float ce_s  = red[0][1] + red[1][1] + red[2][1] + red[3][1];
    float cnt_s = red[0][2] + red[1][2] + red[2][2] + red[3][2];
    out[0] = 0.1f * (dmi_s * (1.f / (float)B_)) + ce_s / cnt_s;
  }
}

extern "C" void kernel_launch(void* const* d_in, const int* in_sizes, int n_in,
                              void* d_out, int out_size, void* d_ws, size_t ws_size,
                              hipStream_t stream) {
  const float* pred = (const float*)d_in[0];
  const int* labels = (const int*)d_in[1];
  float* out = (float*)d_out;
  float* rowout = (float*)d_ws;  // B_ * 4 floats = 4 KiB

  dmice_row<<<B_, THREADS, 0, stream>>>(pred, labels, rowout);
  dmice_final<<<1, 256, 0, stream>>>(rowout, out);
}